// Round 1
// baseline (8296.499 us; speedup 1.0000x reference)
//
#include <hip/hip_runtime.h>

#define EPS   1e-5f
#define SLOPE 0.01f

// ---------------------------------------------------------------------------
// conv 3x3x3, pad=1, cross-correlation. in: [CIN][D][H][W], wt: [Cout][CIN][3][3][3]
// one thread per (cout, voxel)
// ---------------------------------------------------------------------------
template <int CIN>
__global__ void conv3_kernel(const float* __restrict__ in, const float* __restrict__ wt,
                             float* __restrict__ out, int D, int H, int W, int total) {
    const int V   = D * H * W;
    const int idx = blockIdx.x * blockDim.x + threadIdx.x;
    if (idx >= total) return;
    const int co = idx / V;
    const int v  = idx - co * V;
    const int w  = v % W;
    const int h  = (v / W) % H;
    const int d  = v / (W * H);

    float acc = 0.f;
    const float* wbase = wt + (size_t)co * CIN * 27;
#pragma unroll
    for (int kd = 0; kd < 3; ++kd) {
        const int zd = d + kd - 1;
        if (zd < 0 || zd >= D) continue;
#pragma unroll
        for (int kh = 0; kh < 3; ++kh) {
            const int zh = h + kh - 1;
            if (zh < 0 || zh >= H) continue;
#pragma unroll
            for (int kw = 0; kw < 3; ++kw) {
                const int zw = w + kw - 1;
                if (zw < 0 || zw >= W) continue;
                const int sp = (zd * H + zh) * W + zw;
                const float* ip = in + sp;
                const float* wp = wbase + (kd * 3 + kh) * 3 + kw;
#pragma unroll
                for (int ci = 0; ci < CIN; ++ci) {
                    acc = fmaf(ip[(size_t)ci * V], wp[(size_t)ci * 27], acc);
                }
            }
        }
    }
    out[idx] = acc;
}

// ---------------------------------------------------------------------------
// per-channel mean / rstd (biased variance). one block per channel.
// stats[2c] = mean, stats[2c+1] = rsqrt(var+eps)
// ---------------------------------------------------------------------------
__global__ void bn_stats_kernel(const float* __restrict__ x, float* __restrict__ stats, int V) {
    const int c = blockIdx.x;
    const float* p = x + (size_t)c * V;
    float s = 0.f, ss = 0.f;
    for (int i = threadIdx.x; i < V; i += blockDim.x) {
        const float v = p[i];
        s += v;
        ss = fmaf(v, v, ss);
    }
#pragma unroll
    for (int off = 32; off > 0; off >>= 1) {
        s  += __shfl_down(s, off, 64);
        ss += __shfl_down(ss, off, 64);
    }
    __shared__ float sh_s[4], sh_ss[4];
    const int wid  = threadIdx.x >> 6;
    const int lane = threadIdx.x & 63;
    if (lane == 0) { sh_s[wid] = s; sh_ss[wid] = ss; }
    __syncthreads();
    if (threadIdx.x == 0) {
        s  = sh_s[0] + sh_s[1] + sh_s[2] + sh_s[3];
        ss = sh_ss[0] + sh_ss[1] + sh_ss[2] + sh_ss[3];
        const float inv  = 1.f / (float)V;
        const float mean = s * inv;
        const float var  = ss * inv - mean * mean;
        stats[2 * c]     = mean;
        stats[2 * c + 1] = rsqrtf(var + EPS);
    }
}

// ---------------------------------------------------------------------------
// BN normalize + LeakyReLU, in place
// ---------------------------------------------------------------------------
__global__ void bn_apply_kernel(float* __restrict__ x, const float* __restrict__ stats,
                                int V, int total) {
    const int idx = blockIdx.x * blockDim.x + threadIdx.x;
    if (idx >= total) return;
    const int c = idx / V;
    const float mean = stats[2 * c];
    const float rstd = stats[2 * c + 1];
    const float val  = (x[idx] - mean) * rstd;
    x[idx] = val >= 0.f ? val : SLOPE * val;
}

// ---------------------------------------------------------------------------
// 2x2x2 maxpool stride 2
// ---------------------------------------------------------------------------
__global__ void maxpool_kernel(const float* __restrict__ in, float* __restrict__ out,
                               int D, int H, int W, int total) {
    const int Do = D >> 1, Ho = H >> 1, Wo = W >> 1;
    const int Vo = Do * Ho * Wo;
    const int idx = blockIdx.x * blockDim.x + threadIdx.x;
    if (idx >= total) return;
    const int c  = idx / Vo;
    const int v  = idx - c * Vo;
    const int ow = v % Wo;
    const int oh = (v / Wo) % Ho;
    const int od = v / (Wo * Ho);
    const size_t HW = (size_t)H * W;
    const float* p = in + (size_t)c * D * HW + (size_t)(2 * od) * HW + (size_t)(2 * oh) * W + 2 * ow;
    float m = p[0];
    m = fmaxf(m, p[1]);
    m = fmaxf(m, p[W]);
    m = fmaxf(m, p[W + 1]);
    m = fmaxf(m, p[HW]);
    m = fmaxf(m, p[HW + 1]);
    m = fmaxf(m, p[HW + W]);
    m = fmaxf(m, p[HW + W + 1]);
    out[idx] = m;
}

// ---------------------------------------------------------------------------
// ConvTranspose-as-circular-conv: NN-upsample x2 + circular convolution with
// 2x2x2 kernel (true convolution: y[n] = sum_k w[k] x[(n-k) mod N]).
// in: [CIN][Di][Hi][Wi], wt: [Cout][CIN][2][2][2], out: [Cout][2Di][2Hi][2Wi]
// ---------------------------------------------------------------------------
template <int CIN>
__global__ void upconv_kernel(const float* __restrict__ in, const float* __restrict__ wt,
                              float* __restrict__ out, int Di, int Hi, int Wi, int total) {
    const int Do = Di * 2, Ho = Hi * 2, Wo = Wi * 2;
    const int Vo = Do * Ho * Wo;
    const int Vi = Di * Hi * Wi;
    const int idx = blockIdx.x * blockDim.x + threadIdx.x;
    if (idx >= total) return;
    const int co = idx / Vo;
    const int v  = idx - co * Vo;
    const int ow = v % Wo;
    const int oh = (v / Wo) % Ho;
    const int od = v / (Wo * Ho);

    float acc = 0.f;
    const float* wbase = wt + (size_t)co * CIN * 8;
#pragma unroll
    for (int kd = 0; kd < 2; ++kd) {
        int td = od - kd; if (td < 0) td += Do;
        const int id = td >> 1;
#pragma unroll
        for (int kh = 0; kh < 2; ++kh) {
            int th = oh - kh; if (th < 0) th += Ho;
            const int ih = th >> 1;
#pragma unroll
            for (int kw = 0; kw < 2; ++kw) {
                int tw = ow - kw; if (tw < 0) tw += Wo;
                const int iw = tw >> 1;
                const int sp = (id * Hi + ih) * Wi + iw;
                const float* ip = in + sp;
                const float* wp = wbase + (kd * 2 + kh) * 2 + kw;
#pragma unroll
                for (int ci = 0; ci < CIN; ++ci) {
                    acc = fmaf(ip[(size_t)ci * Vi], wp[(size_t)ci * 8], acc);
                }
            }
        }
    }
    out[idx] = acc;
}

// ---------------------------------------------------------------------------
// final 1x1x1 conv + bias
// ---------------------------------------------------------------------------
__global__ void final_kernel(const float* __restrict__ in, const float* __restrict__ w,
                             const float* __restrict__ b, float* __restrict__ out, int C, int V) {
    const int idx = blockIdx.x * blockDim.x + threadIdx.x;
    if (idx >= V) return;
    float acc = b[0];
    for (int c = 0; c < C; ++c)
        acc = fmaf(in[(size_t)c * V + idx], w[c], acc);
    out[idx] = acc;
}

// ---------------------------------------------------------------------------

extern "C" void kernel_launch(void* const* d_in, const int* in_sizes, int n_in,
                              void* d_out, int out_size, void* d_ws, size_t ws_size,
                              hipStream_t stream) {
    const float* x      = (const float*)d_in[0];
    const float* wf1    = (const float*)d_in[1];
    const float* wf2    = (const float*)d_in[2];
    const float* wd1a   = (const float*)d_in[3];
    const float* wd1b   = (const float*)d_in[4];
    const float* wd2a   = (const float*)d_in[5];
    const float* wd2b   = (const float*)d_in[6];
    const float* wd3a   = (const float*)d_in[7];
    const float* wd3b   = (const float*)d_in[8];
    const float* wt1    = (const float*)d_in[9];
    const float* wu1a   = (const float*)d_in[10];
    const float* wu1b   = (const float*)d_in[11];
    const float* wt2    = (const float*)d_in[12];
    const float* wu2a   = (const float*)d_in[13];
    const float* wu2b   = (const float*)d_in[14];
    const float* wt3    = (const float*)d_in[15];
    const float* wu3a   = (const float*)d_in[16];
    const float* wu3b   = (const float*)d_in[17];
    const float* w_fin  = (const float*)d_in[18];
    const float* b_fin  = (const float*)d_in[19];
    float* out = (float*)d_out;

    const int V0 = 64 * 64 * 64;   // 262144
    const int V1 = 32 * 32 * 32;   // 32768
    const int V2 = 16 * 16 * 16;   // 4096
    const int V3 = 8 * 8 * 8;      // 512

    float* ws   = (float*)d_ws;
    float* cat3 = ws;                         // 32 * V0   (x1 | up3)
    float* cat2 = cat3 + (size_t)32 * V0;     // 64 * V1   (x2 | up2)
    float* cat1 = cat2 + (size_t)64 * V1;     // 128 * V2  (x3 | up1)
    float* x4   = cat1 + (size_t)128 * V2;    // 128 * V3
    float* tA   = x4   + (size_t)128 * V3;    // 16 * V0
    float* tB   = tA   + (size_t)16 * V0;     // 16 * V0
    float* stats= tB   + (size_t)16 * V0;     // 256

    const int TB = 256;
    auto blocks = [](int n) { return (n + 255) / 256; };

    auto conv_launch = [&](const float* in, const float* wt, float* o,
                           int Cin, int Cout, int D, int H, int W) {
        const int total = Cout * D * H * W;
        switch (Cin) {
            case 1:   hipLaunchKernelGGL((conv3_kernel<1>),   dim3(blocks(total)), dim3(TB), 0, stream, in, wt, o, D, H, W, total); break;
            case 16:  hipLaunchKernelGGL((conv3_kernel<16>),  dim3(blocks(total)), dim3(TB), 0, stream, in, wt, o, D, H, W, total); break;
            case 32:  hipLaunchKernelGGL((conv3_kernel<32>),  dim3(blocks(total)), dim3(TB), 0, stream, in, wt, o, D, H, W, total); break;
            case 64:  hipLaunchKernelGGL((conv3_kernel<64>),  dim3(blocks(total)), dim3(TB), 0, stream, in, wt, o, D, H, W, total); break;
            case 128: hipLaunchKernelGGL((conv3_kernel<128>), dim3(blocks(total)), dim3(TB), 0, stream, in, wt, o, D, H, W, total); break;
        }
    };
    auto bn_lrelu = [&](float* o, int C, int V) {
        hipLaunchKernelGGL(bn_stats_kernel, dim3(C), dim3(TB), 0, stream, o, stats, V);
        hipLaunchKernelGGL(bn_apply_kernel, dim3(blocks(C * V)), dim3(TB), 0, stream, o, stats, V, C * V);
    };
    auto conv_bn = [&](const float* in, const float* wt, float* o,
                       int Cin, int Cout, int D, int H, int W) {
        conv_launch(in, wt, o, Cin, Cout, D, H, W);
        bn_lrelu(o, Cout, D * H * W);
    };
    auto upconv_bn = [&](const float* in, const float* wt, float* o,
                         int Cin, int Cout, int Di, int Hi, int Wi) {
        const int total = Cout * 8 * Di * Hi * Wi;
        switch (Cin) {
            case 32:  hipLaunchKernelGGL((upconv_kernel<32>),  dim3(blocks(total)), dim3(TB), 0, stream, in, wt, o, Di, Hi, Wi, total); break;
            case 64:  hipLaunchKernelGGL((upconv_kernel<64>),  dim3(blocks(total)), dim3(TB), 0, stream, in, wt, o, Di, Hi, Wi, total); break;
            case 128: hipLaunchKernelGGL((upconv_kernel<128>), dim3(blocks(total)), dim3(TB), 0, stream, in, wt, o, Di, Hi, Wi, total); break;
        }
        bn_lrelu(o, Cout, 8 * Di * Hi * Wi);
    };
    auto maxpool = [&](const float* in, float* o, int C, int D, int H, int W) {
        const int total = C * (D / 2) * (H / 2) * (W / 2);
        hipLaunchKernelGGL(maxpool_kernel, dim3(blocks(total)), dim3(TB), 0, stream, in, o, D, H, W, total);
    };

    // ----- encoder -----
    conv_bn(x, wf1, tA, 1, 16, 64, 64, 64);            // tA = lrelu(bn(conv(x)))
    conv_bn(tA, wf2, cat3, 16, 16, 64, 64, 64);        // x1 -> cat3[0:16]
    maxpool(cat3, tA, 16, 64, 64, 64);                 // tA[16,V1]
    conv_bn(tA, wd1a, tB, 16, 32, 32, 32, 32);
    conv_bn(tB, wd1b, cat2, 32, 32, 32, 32, 32);       // x2 -> cat2[0:32]
    maxpool(cat2, tA, 32, 32, 32, 32);                 // tA[32,V2]
    conv_bn(tA, wd2a, tB, 32, 64, 16, 16, 16);
    conv_bn(tB, wd2b, cat1, 64, 64, 16, 16, 16);       // x3 -> cat1[0:64]
    maxpool(cat1, tA, 64, 16, 16, 16);                 // tA[64,V3]
    conv_bn(tA, wd3a, tB, 64, 128, 8, 8, 8);
    conv_bn(tB, wd3b, x4, 128, 128, 8, 8, 8);          // x4

    // ----- decoder -----
    upconv_bn(x4, wt1, cat1 + (size_t)64 * V2, 128, 64, 8, 8, 8);     // up1 -> cat1[64:128]
    conv_bn(cat1, wu1a, tA, 128, 64, 16, 16, 16);
    conv_bn(tA, wu1b, tB, 64, 64, 16, 16, 16);

    upconv_bn(tB, wt2, cat2 + (size_t)32 * V1, 64, 32, 16, 16, 16);   // up2 -> cat2[32:64]
    conv_bn(cat2, wu2a, tA, 64, 32, 32, 32, 32);
    conv_bn(tA, wu2b, tB, 32, 32, 32, 32, 32);

    upconv_bn(tB, wt3, cat3 + (size_t)16 * V0, 32, 16, 32, 32, 32);   // up3 -> cat3[16:32]
    conv_bn(cat3, wu3a, tA, 32, 16, 64, 64, 64);
    conv_bn(tA, wu3b, tB, 16, 16, 64, 64, 64);

    // ----- final 1x1x1 conv + bias -----
    hipLaunchKernelGGL(final_kernel, dim3(blocks(V0)), dim3(TB), 0, stream,
                       tB, w_fin, b_fin, out, 16, V0);
}

// Round 2
// 3207.792 us; speedup vs baseline: 2.5864x; 2.5864x over previous
//
#include <hip/hip_runtime.h>

#define EPS   1e-5f
#define SLOPE 0.01f

// ---------------------------------------------------------------------------
// conv 3x3x3 pad=1 (cross-correlation), cout-register-blocked.
// in: [CIN][D][H][W], wt: [Cout][CIN][3][3][3]
// thread -> VOXB voxels (stride 256), COB output channels (co0 = blockIdx.y*COB)
// weights staged to LDS as [tap][ci][co] (broadcast reads, conflict-free)
// ---------------------------------------------------------------------------
template <int CIN, int COB, int VOXB>
__global__ __launch_bounds__(256) void conv3_v3(const float* __restrict__ in,
                                                const float* __restrict__ wt,
                                                float* __restrict__ out,
                                                int D, int H, int W) {
    const int V = D * H * W;
    __shared__ float wlds[COB * CIN * 27];
    const int co0 = blockIdx.y * COB;
    for (int i = threadIdx.x; i < COB * CIN * 27; i += 256) {
        const int tap = i / (CIN * COB);
        const int r   = i - tap * (CIN * COB);
        const int ci  = r / COB;
        const int co  = r - ci * COB;
        wlds[i] = wt[((size_t)(co0 + co) * CIN + ci) * 27 + tap];
    }
    __syncthreads();

    const int vbase = blockIdx.x * (256 * VOXB) + threadIdx.x;
    int dd[VOXB], hh[VOXB], ww[VOXB];
#pragma unroll
    for (int j = 0; j < VOXB; ++j) {
        const int v = vbase + j * 256;
        ww[j] = v % W;
        hh[j] = (v / W) % H;
        dd[j] = v / (W * H);
    }
    float acc[COB * VOXB];
#pragma unroll
    for (int i = 0; i < COB * VOXB; ++i) acc[i] = 0.f;

#pragma unroll
    for (int kd = 0; kd < 3; ++kd) {
#pragma unroll
        for (int kh = 0; kh < 3; ++kh) {
#pragma unroll
            for (int kw = 0; kw < 3; ++kw) {
                const int tap = (kd * 3 + kh) * 3 + kw;
                int  sp[VOXB];
                bool ok[VOXB];
#pragma unroll
                for (int j = 0; j < VOXB; ++j) {
                    const int zd = dd[j] + kd - 1;
                    const int zh = hh[j] + kh - 1;
                    const int zw = ww[j] + kw - 1;
                    ok[j] = ((unsigned)zd < (unsigned)D) &
                            ((unsigned)zh < (unsigned)H) &
                            ((unsigned)zw < (unsigned)W);
                    sp[j] = (zd * H + zh) * W + zw;
                }
                const float* wrow = &wlds[tap * CIN * COB];
                for (int ci = 0; ci < CIN; ++ci) {
                    float xv[VOXB];
#pragma unroll
                    for (int j = 0; j < VOXB; ++j)
                        xv[j] = ok[j] ? in[(size_t)ci * V + sp[j]] : 0.f;
                    const float* wp = wrow + ci * COB;
#pragma unroll
                    for (int co = 0; co < COB; ++co) {
                        const float wgt = wp[co];
#pragma unroll
                        for (int j = 0; j < VOXB; ++j)
                            acc[co * VOXB + j] = fmaf(xv[j], wgt, acc[co * VOXB + j]);
                    }
                }
            }
        }
    }
#pragma unroll
    for (int co = 0; co < COB; ++co)
#pragma unroll
        for (int j = 0; j < VOXB; ++j)
            out[(size_t)(co0 + co) * V + vbase + j * 256] = acc[co * VOXB + j];
}

// ---------------------------------------------------------------------------
// upconv (NN-upsample x2 + circular 2x2x2 true convolution), cout-blocked.
// in: [CIN][Di][Hi][Wi], wt: [Cout][CIN][2][2][2], out: [Cout][2Di][2Hi][2Wi]
// ---------------------------------------------------------------------------
template <int CIN, int COB, int VOXB>
__global__ __launch_bounds__(256) void upconv_v3(const float* __restrict__ in,
                                                 const float* __restrict__ wt,
                                                 float* __restrict__ out,
                                                 int Di, int Hi, int Wi) {
    const int Do = 2 * Di, Ho = 2 * Hi, Wo = 2 * Wi;
    const int Vo = Do * Ho * Wo;
    const int Vi = Di * Hi * Wi;
    __shared__ float wlds[COB * CIN * 8];
    const int co0 = blockIdx.y * COB;
    for (int i = threadIdx.x; i < COB * CIN * 8; i += 256) {
        const int tap = i / (CIN * COB);
        const int r   = i - tap * (CIN * COB);
        const int ci  = r / COB;
        const int co  = r - ci * COB;
        wlds[i] = wt[((size_t)(co0 + co) * CIN + ci) * 8 + tap];
    }
    __syncthreads();

    const int vbase = blockIdx.x * (256 * VOXB) + threadIdx.x;
    int od[VOXB], oh[VOXB], ow[VOXB];
#pragma unroll
    for (int j = 0; j < VOXB; ++j) {
        const int v = vbase + j * 256;
        ow[j] = v % Wo;
        oh[j] = (v / Wo) % Ho;
        od[j] = v / (Wo * Ho);
    }
    float acc[COB * VOXB];
#pragma unroll
    for (int i = 0; i < COB * VOXB; ++i) acc[i] = 0.f;

#pragma unroll
    for (int kd = 0; kd < 2; ++kd) {
#pragma unroll
        for (int kh = 0; kh < 2; ++kh) {
#pragma unroll
            for (int kw = 0; kw < 2; ++kw) {
                const int tap = (kd * 2 + kh) * 2 + kw;
                int sp[VOXB];
#pragma unroll
                for (int j = 0; j < VOXB; ++j) {
                    const int id = ((od[j] - kd + Do) & (Do - 1)) >> 1;
                    const int ih = ((oh[j] - kh + Ho) & (Ho - 1)) >> 1;
                    const int iw = ((ow[j] - kw + Wo) & (Wo - 1)) >> 1;
                    sp[j] = (id * Hi + ih) * Wi + iw;
                }
                const float* wrow = &wlds[tap * CIN * COB];
                for (int ci = 0; ci < CIN; ++ci) {
                    float xv[VOXB];
#pragma unroll
                    for (int j = 0; j < VOXB; ++j)
                        xv[j] = in[(size_t)ci * Vi + sp[j]];
                    const float* wp = wrow + ci * COB;
#pragma unroll
                    for (int co = 0; co < COB; ++co) {
                        const float wgt = wp[co];
#pragma unroll
                        for (int j = 0; j < VOXB; ++j)
                            acc[co * VOXB + j] = fmaf(xv[j], wgt, acc[co * VOXB + j]);
                    }
                }
            }
        }
    }
#pragma unroll
    for (int co = 0; co < COB; ++co)
#pragma unroll
        for (int j = 0; j < VOXB; ++j)
            out[(size_t)(co0 + co) * Vo + vbase + j * 256] = acc[co * VOXB + j];
}

// ---------------------------------------------------------------------------
// BN stats: partial sums per (channel, segment), then finalize.
// part layout: [C][S][2] (sum, sumsq). stats: [C][2] (mean, rstd)
// ---------------------------------------------------------------------------
__global__ __launch_bounds__(256) void bn_stats_part(const float* __restrict__ x,
                                                     float* __restrict__ part,
                                                     int V, int chunk) {
    const int c = blockIdx.x, s = blockIdx.y;
    const float* p = x + (size_t)c * V + (size_t)s * chunk;
    float s1 = 0.f, s2 = 0.f;
    for (int i = threadIdx.x * 4; i < chunk; i += 256 * 4) {
        const float4 v = *(const float4*)(p + i);
        s1 += v.x + v.y + v.z + v.w;
        s2 = fmaf(v.x, v.x, s2);
        s2 = fmaf(v.y, v.y, s2);
        s2 = fmaf(v.z, v.z, s2);
        s2 = fmaf(v.w, v.w, s2);
    }
#pragma unroll
    for (int off = 32; off > 0; off >>= 1) {
        s1 += __shfl_down(s1, off, 64);
        s2 += __shfl_down(s2, off, 64);
    }
    __shared__ float sh[8];
    const int wid  = threadIdx.x >> 6;
    const int lane = threadIdx.x & 63;
    if (lane == 0) { sh[wid] = s1; sh[4 + wid] = s2; }
    __syncthreads();
    if (threadIdx.x == 0) {
        part[(c * gridDim.y + s) * 2]     = sh[0] + sh[1] + sh[2] + sh[3];
        part[(c * gridDim.y + s) * 2 + 1] = sh[4] + sh[5] + sh[6] + sh[7];
    }
}

__global__ __launch_bounds__(64) void bn_stats_final(const float* __restrict__ part,
                                                     float* __restrict__ stats,
                                                     int S, int V) {
    const int c = blockIdx.x;
    float s1 = 0.f, s2 = 0.f;
    if ((int)threadIdx.x < S) {
        s1 = part[(c * S + threadIdx.x) * 2];
        s2 = part[(c * S + threadIdx.x) * 2 + 1];
    }
#pragma unroll
    for (int off = 32; off > 0; off >>= 1) {
        s1 += __shfl_down(s1, off, 64);
        s2 += __shfl_down(s2, off, 64);
    }
    if (threadIdx.x == 0) {
        const float inv  = 1.f / (float)V;
        const float mean = s1 * inv;
        const float var  = s2 * inv - mean * mean;
        stats[2 * c]     = mean;
        stats[2 * c + 1] = rsqrtf(var + EPS);
    }
}

// ---------------------------------------------------------------------------
// BN normalize + LeakyReLU, in place, float4
// ---------------------------------------------------------------------------
__global__ __launch_bounds__(256) void bn_apply_v2(float* __restrict__ x,
                                                   const float* __restrict__ stats,
                                                   int V4, int total4) {
    const int idx = blockIdx.x * blockDim.x + threadIdx.x;
    if (idx >= total4) return;
    const int c = idx / V4;
    const float mean = stats[2 * c];
    const float rstd = stats[2 * c + 1];
    float4 v = ((float4*)x)[idx];
    float t;
    t = (v.x - mean) * rstd; v.x = t >= 0.f ? t : SLOPE * t;
    t = (v.y - mean) * rstd; v.y = t >= 0.f ? t : SLOPE * t;
    t = (v.z - mean) * rstd; v.z = t >= 0.f ? t : SLOPE * t;
    t = (v.w - mean) * rstd; v.w = t >= 0.f ? t : SLOPE * t;
    ((float4*)x)[idx] = v;
}

// ---------------------------------------------------------------------------
// 2x2x2 maxpool stride 2
// ---------------------------------------------------------------------------
__global__ __launch_bounds__(256) void maxpool_kernel(const float* __restrict__ in,
                                                      float* __restrict__ out,
                                                      int D, int H, int W, int total) {
    const int Do = D >> 1, Ho = H >> 1, Wo = W >> 1;
    const int Vo = Do * Ho * Wo;
    const int idx = blockIdx.x * blockDim.x + threadIdx.x;
    if (idx >= total) return;
    const int c  = idx / Vo;
    const int v  = idx - c * Vo;
    const int ow = v % Wo;
    const int oh = (v / Wo) % Ho;
    const int od = v / (Wo * Ho);
    const size_t HW = (size_t)H * W;
    const float* p = in + (size_t)c * D * HW + (size_t)(2 * od) * HW + (size_t)(2 * oh) * W + 2 * ow;
    float m = p[0];
    m = fmaxf(m, p[1]);
    m = fmaxf(m, p[W]);
    m = fmaxf(m, p[W + 1]);
    m = fmaxf(m, p[HW]);
    m = fmaxf(m, p[HW + 1]);
    m = fmaxf(m, p[HW + W]);
    m = fmaxf(m, p[HW + W + 1]);
    out[idx] = m;
}

// ---------------------------------------------------------------------------
// final 1x1x1 conv + bias, float4
// ---------------------------------------------------------------------------
__global__ __launch_bounds__(256) void final_v2(const float* __restrict__ in,
                                                const float* __restrict__ w,
                                                const float* __restrict__ b,
                                                float* __restrict__ out, int C, int V4) {
    const int idx = blockIdx.x * blockDim.x + threadIdx.x;
    if (idx >= V4) return;
    const float bb = b[0];
    float4 acc = make_float4(bb, bb, bb, bb);
    for (int c = 0; c < C; ++c) {
        const float4 v = ((const float4*)in)[(size_t)c * V4 + idx];
        const float wc = w[c];
        acc.x = fmaf(v.x, wc, acc.x);
        acc.y = fmaf(v.y, wc, acc.y);
        acc.z = fmaf(v.z, wc, acc.z);
        acc.w = fmaf(v.w, wc, acc.w);
    }
    ((float4*)out)[idx] = acc;
}

// ---------------------------------------------------------------------------

extern "C" void kernel_launch(void* const* d_in, const int* in_sizes, int n_in,
                              void* d_out, int out_size, void* d_ws, size_t ws_size,
                              hipStream_t stream) {
    const float* x      = (const float*)d_in[0];
    const float* wf1    = (const float*)d_in[1];
    const float* wf2    = (const float*)d_in[2];
    const float* wd1a   = (const float*)d_in[3];
    const float* wd1b   = (const float*)d_in[4];
    const float* wd2a   = (const float*)d_in[5];
    const float* wd2b   = (const float*)d_in[6];
    const float* wd3a   = (const float*)d_in[7];
    const float* wd3b   = (const float*)d_in[8];
    const float* wt1    = (const float*)d_in[9];
    const float* wu1a   = (const float*)d_in[10];
    const float* wu1b   = (const float*)d_in[11];
    const float* wt2    = (const float*)d_in[12];
    const float* wu2a   = (const float*)d_in[13];
    const float* wu2b   = (const float*)d_in[14];
    const float* wt3    = (const float*)d_in[15];
    const float* wu3a   = (const float*)d_in[16];
    const float* wu3b   = (const float*)d_in[17];
    const float* w_fin  = (const float*)d_in[18];
    const float* b_fin  = (const float*)d_in[19];
    float* out = (float*)d_out;

    const int V0 = 64 * 64 * 64;
    const int V1 = 32 * 32 * 32;
    const int V2 = 16 * 16 * 16;
    const int V3 = 8 * 8 * 8;

    float* ws   = (float*)d_ws;
    float* cat3 = ws;                         // 32 * V0   (x1 | up3)
    float* cat2 = cat3 + (size_t)32 * V0;     // 64 * V1   (x2 | up2)
    float* cat1 = cat2 + (size_t)64 * V1;     // 128 * V2  (x3 | up1)
    float* x4   = cat1 + (size_t)128 * V2;    // 128 * V3
    float* tA   = x4   + (size_t)128 * V3;    // 16 * V0
    float* tB   = tA   + (size_t)16 * V0;     // 16 * V0
    float* stats= tB   + (size_t)16 * V0;     // 256
    float* part = stats + 256;                // up to 128*16*2 = 4096

    const int TB = 256;
    auto blocks = [](int n) { return (n + 255) / 256; };

    auto bn_lrelu = [&](float* o, int C, int V) {
        const int S = (V == V0) ? 16 : (V == V1) ? 8 : (V == V2) ? 2 : 1;
        hipLaunchKernelGGL(bn_stats_part, dim3(C, S), dim3(TB), 0, stream, o, part, V, V / S);
        hipLaunchKernelGGL(bn_stats_final, dim3(C), dim3(64), 0, stream, part, stats, S, V);
        const int total4 = C * V / 4;
        hipLaunchKernelGGL(bn_apply_v2, dim3(blocks(total4)), dim3(TB), 0, stream, o, stats, V / 4, total4);
    };
    auto maxpool = [&](const float* in, float* o, int C, int D, int H, int W) {
        const int total = C * (D / 2) * (H / 2) * (W / 2);
        hipLaunchKernelGGL(maxpool_kernel, dim3(blocks(total)), dim3(TB), 0, stream, in, o, D, H, W, total);
    };

    // macro-ish helpers for templated conv launches
#define CONV(CIN, COB, VOXB, in_, wt_, out_, Cout, D_, H_, W_)                              \
    {                                                                                       \
        const int V_ = (D_) * (H_) * (W_);                                                  \
        dim3 g(V_ / (256 * (VOXB)), (Cout) / (COB));                                        \
        hipLaunchKernelGGL((conv3_v3<CIN, COB, VOXB>), g, dim3(TB), 0, stream,              \
                           in_, wt_, out_, D_, H_, W_);                                     \
        bn_lrelu(out_, Cout, V_);                                                           \
    }
#define UPCONV(CIN, COB, VOXB, in_, wt_, out_, Cout, Di_, Hi_, Wi_)                         \
    {                                                                                       \
        const int Vo_ = 8 * (Di_) * (Hi_) * (Wi_);                                          \
        dim3 g(Vo_ / (256 * (VOXB)), (Cout) / (COB));                                       \
        hipLaunchKernelGGL((upconv_v3<CIN, COB, VOXB>), g, dim3(TB), 0, stream,             \
                           in_, wt_, out_, Di_, Hi_, Wi_);                                  \
        bn_lrelu(out_, Cout, Vo_);                                                          \
    }

    // ----- encoder -----
    CONV(1,  16, 4, x,   wf1, tA,   16, 64, 64, 64);
    CONV(16, 16, 4, tA,  wf2, cat3, 16, 64, 64, 64);          // x1 -> cat3[0:16]
    maxpool(cat3, tA, 16, 64, 64, 64);
    CONV(16, 16, 4, tA,  wd1a, tB,  32, 32, 32, 32);
    CONV(32, 8,  4, tB,  wd1b, cat2, 32, 32, 32, 32);         // x2 -> cat2[0:32]
    maxpool(cat2, tA, 32, 32, 32, 32);
    CONV(32, 8,  2, tA,  wd2a, tB,  64, 16, 16, 16);
    CONV(64, 4,  2, tB,  wd2b, cat1, 64, 16, 16, 16);         // x3 -> cat1[0:64]
    maxpool(cat1, tA, 64, 16, 16, 16);
    CONV(64, 4,  2, tA,  wd3a, tB,  128, 8, 8, 8);
    CONV(128, 4, 2, tB,  wd3b, x4,  128, 8, 8, 8);            // x4

    // ----- decoder -----
    UPCONV(128, 4, 2, x4, wt1, cat1 + (size_t)64 * V2, 64, 8, 8, 8);     // up1 -> cat1[64:]
    CONV(128, 4, 2, cat1, wu1a, tA, 64, 16, 16, 16);
    CONV(64,  4, 2, tA,   wu1b, tB, 64, 16, 16, 16);

    UPCONV(64, 8, 4, tB, wt2, cat2 + (size_t)32 * V1, 32, 16, 16, 16);   // up2 -> cat2[32:]
    CONV(64, 4, 4, cat2, wu2a, tA, 32, 32, 32, 32);
    CONV(32, 8, 4, tA,   wu2b, tB, 32, 32, 32, 32);

    UPCONV(32, 16, 4, tB, wt3, cat3 + (size_t)16 * V0, 16, 32, 32, 32);  // up3 -> cat3[16:]
    CONV(32, 8, 4, cat3, wu3a, tA, 16, 64, 64, 64);
    CONV(16, 16, 4, tA,  wu3b, tB, 16, 64, 64, 64);

    // ----- final 1x1x1 conv + bias -----
    hipLaunchKernelGGL(final_v2, dim3(blocks(V0 / 4)), dim3(TB), 0, stream,
                       tB, w_fin, b_fin, out, 16, V0 / 4);

#undef CONV
#undef UPCONV
}